// Round 13
// baseline (4255.828 us; speedup 1.0000x reference)
//
#include <hip/hip_runtime.h>

// RNN + FC readout on MI355X — f32 recurrence, quarter-split, wave-specialized single-barrier
// step with tagged single-RTT exchange.
//   A: xp[B,T,H] = input @ w_ih^T + b_h   (f32 GEMM; cols 0..255 -> d_out, 256..511 -> d_ws)
//   B: h_t = tanh(xp_t + h_{t-1} @ w_hh^T): 256 blocks = 4/batch; W quarter all-register.
//      Thread t owns global row t. Wave ks reads hl[par][ks*64..+64) — a slice written by
//      ITSELF (own waves: finalize; partner waves: probe) -> same-wave LDS in-order, no
//      barrier. Single lgkm-barrier per step guards pacc (double-buffered by parity).
//      Partner waves skip finalize and overlap their spin with own-waves' finalize.
//   C: out[B,T,O] = h @ w_out^T + b_out   (f16-dot2 GEMM, f32 in-place over d_out)
//
// Proven-refuted: f16 W/h in recurrence (R7), 2-batch interleave (R10), vmcnt-drain as
// main cost (R12: -6%). R11-proven: tagged u64 exchange. R12-proven: lgkm-only barriers.

typedef _Float16 f16;
typedef __attribute__((ext_vector_type(2))) _Float16 half2_t;
typedef __attribute__((ext_vector_type(4))) float float4_t;

#define NIN    256
#define NHID   512
#define NOUT   256
#define NBATCH 64
#define NT     2048

#define FL4(p) (*reinterpret_cast<const float4_t*>(p))
#define LOADA(p)     __hip_atomic_load((p), __ATOMIC_RELAXED, __HIP_MEMORY_SCOPE_AGENT)
#define STOREA(p, v) __hip_atomic_store((p), (v), __ATOMIC_RELAXED, __HIP_MEMORY_SCOPE_AGENT)

// LDS-only barrier: orders ds ops across the workgroup WITHOUT draining vmcnt (R12-proven).
#define LDS_BAR() do {                                              \
    asm volatile("s_waitcnt lgkmcnt(0)\n\ts_barrier" ::: "memory"); \
    __builtin_amdgcn_sched_barrier(0);                              \
  } while (0)

#if __has_builtin(__builtin_amdgcn_fdot2)
__device__ __forceinline__ float fdot2f(half2_t a, half2_t b, float c) {
  return __builtin_amdgcn_fdot2(a, b, c, false);   // v_dot2_f32_f16 (phase C only)
}
#else
__device__ __forceinline__ float fdot2f(half2_t a, half2_t b, float c) {
  return c + (float)a.x * (float)b.x + (float)a.y * (float)b.y;
}
#endif

__device__ __forceinline__ float tanh_fast(float x) {   // R5/R12-proven
  float e = __expf(2.0f * x);
  return 1.0f - 2.0f / (e + 1.0f);
}

__device__ unsigned long long g_pub[NBATCH][2][NHID];   // (tag s+1)<<32 | f32 bits; 512 KB

__global__ __launch_bounds__(256) void k_zero() {
  ((unsigned long long*)g_pub)[blockIdx.x * 256 + threadIdx.x] = 0ull;   // grid 256
}

// ---------------- Phase A: in-projection GEMM, full f32 (proven R5..R12) ----------------
__global__ __launch_bounds__(256) void k_inproj(
    const float* __restrict__ x, const float* __restrict__ w,
    const float* __restrict__ bias, float* __restrict__ xplo, float* __restrict__ xphi)
{
  __shared__ float xs[32][260];
  __shared__ float wsT[8][520];
  const int t = threadIdx.x;
  const int m0 = blockIdx.x * 32;
  const int mthr = t & 3;
  const int nthr = t >> 2;

  #pragma unroll
  for (int r = 0; r < 8; ++r) {
    int f = (t + 256 * r) * 4;
    int row = f >> 8, col = f & 255;
    *(float4_t*)&xs[row][col] =
        *reinterpret_cast<const float4_t*>(x + (size_t)(m0 + row) * NIN + col);
  }

  float acc[8][8];
  #pragma unroll
  for (int nn = 0; nn < 8; ++nn) {
    float bv = bias[nthr * 8 + nn];
    #pragma unroll
    for (int mm = 0; mm < 8; ++mm) acc[nn][mm] = bv;
  }

  for (int kc = 0; kc < 32; ++kc) {
    __syncthreads();
    #pragma unroll
    for (int r = 0; r < 4; ++r) {
      int f = (t + 256 * r) * 4;
      int n = f >> 3, k0 = f & 7;
      float4_t v = *reinterpret_cast<const float4_t*>(w + (size_t)n * NIN + kc * 8 + k0);
      #pragma unroll
      for (int j = 0; j < 4; ++j) wsT[k0 + j][n] = v[j];
    }
    __syncthreads();
    #pragma unroll
    for (int kp = 0; kp < 8; ++kp) {
      float4_t wv0 = *(const float4_t*)&wsT[kp][nthr * 8];
      float4_t wv1 = *(const float4_t*)&wsT[kp][nthr * 8 + 4];
      #pragma unroll
      for (int mm = 0; mm < 8; ++mm) {
        float xv = xs[mthr * 8 + mm][kc * 8 + kp];
        acc[0][mm] = fmaf(wv0.x, xv, acc[0][mm]);
        acc[1][mm] = fmaf(wv0.y, xv, acc[1][mm]);
        acc[2][mm] = fmaf(wv0.z, xv, acc[2][mm]);
        acc[3][mm] = fmaf(wv0.w, xv, acc[3][mm]);
        acc[4][mm] = fmaf(wv1.x, xv, acc[4][mm]);
        acc[5][mm] = fmaf(wv1.y, xv, acc[5][mm]);
        acc[6][mm] = fmaf(wv1.z, xv, acc[6][mm]);
        acc[7][mm] = fmaf(wv1.w, xv, acc[7][mm]);
      }
    }
  }

  const int n0 = nthr * 8;
  float* dst = (n0 < 256) ? (xplo + n0) : (xphi + (n0 - 256));
  #pragma unroll
  for (int mm = 0; mm < 8; ++mm) {
    int m = m0 + mthr * 8 + mm;
    float4_t o0 = {acc[0][mm], acc[1][mm], acc[2][mm], acc[3][mm]};
    float4_t o1 = {acc[4][mm], acc[5][mm], acc[6][mm], acc[7][mm]};
    *reinterpret_cast<float4_t*>(dst + (size_t)m * 256)     = o0;
    *reinterpret_cast<float4_t*>(dst + (size_t)m * 256 + 4) = o1;
  }
}

// ---------------- Phase B: f32 recurrence, wave-specialized, 1 barrier/step ----------------
// block g: batch b=(g>>5)*8+(g&7), quarter q=(g>>3)&3 owns global rows [q*128,+128).
// thread t (=global row t for probe/finalize): js=t&63 -> W rows r0=q*128+2js, r1;
// ks=t>>6 (wave) -> k-slice [ks*64,+64). ownw = (ks>>1==q).
// Own waves: FMA -> pacc -> BAR -> finalize (sum+tanh+hl write+publish+xp).
// Partner waves: probe g_pub[...][t] (spin, tag-validated) -> hl write -> FMA -> pacc -> BAR.
__global__ __launch_bounds__(512, 1) void k_recur(
    const float* __restrict__ whh, float* outbuf, float* wsbuf)
{
  __shared__ __align__(16) float hl[2][NHID];
  __shared__ __align__(16) float pacc[2][8][128];
  const int g = blockIdx.x;
  const int b = (g >> 5) * 8 + (g & 7);
  const int q = (g >> 3) & 3;
  const int t = threadIdx.x;
  const int js = t & 63;
  const int ks = t >> 6;
  const int r0 = q * 128 + js * 2, r1 = r0 + 1;
  const bool ownw = (ks >> 1) == q;

  float4_t w0[16], w1[16];
  #pragma unroll
  for (int i = 0; i < 16; ++i) {
    w0[i] = FL4(whh + (size_t)r0 * NHID + ks * 64 + i * 4);
    w1[i] = FL4(whh + (size_t)r1 * NHID + ks * 64 + i * 4);
  }

  // own-wave lanes have t in [q*128,+128) == their global row/col
  float* xp = ((t < 256) ? (outbuf + t) : (wsbuf + (t - 256))) + (size_t)b * NT * 256;
  float xq0 = 0.f, xq1 = 0.f;
  if (ownw) { xq0 = xp[0]; xq1 = xp[256]; }

  hl[0][t] = 0.0f;                                  // h_{-1} = 0
  __syncthreads();                                  // prologue: full drain once

  for (int s = 0; s < NT; ++s) {
    const int par = s & 1;

    if (!ownw && s > 0) {                           // probe own row t of the peer block
      unsigned long long pv = LOADA(&g_pub[b][(s - 1) & 1][t]);
      while ((unsigned)(pv >> 32) < (unsigned)s)
        pv = LOADA(&g_pub[b][(s - 1) & 1][t]);
      hl[par][t] = __builtin_bit_cast(float, (unsigned)pv);
      asm volatile("s_waitcnt lgkmcnt(0)" ::: "memory");   // order write -> own b128 reads
      __builtin_amdgcn_sched_barrier(0);
    }

    float4_t a0 = {0.f,0.f,0.f,0.f}, a1 = {0.f,0.f,0.f,0.f};
    float4_t b0 = {0.f,0.f,0.f,0.f}, b1 = {0.f,0.f,0.f,0.f};
    {
      const float4_t* h4 = (const float4_t*)&hl[par][ks * 64];   // written by THIS wave
      #pragma unroll
      for (int i = 0; i < 16; i += 2) {
        float4_t hA = h4[i], hB = h4[i + 1];
        a0 += w0[i] * hA;  a1 += w0[i + 1] * hB;
        b0 += w1[i] * hA;  b1 += w1[i + 1] * hB;
      }
    }
    float4_t av = a0 + a1, bv = b0 + b1;
    pacc[par][ks][js * 2]     = (av.x + av.y) + (av.z + av.w);
    pacc[par][ks][js * 2 + 1] = (bv.x + bv.y) + (bv.z + bv.w);
    LDS_BAR();                                      // the ONLY barrier: pacc(s) complete

    if (ownw) {                                     // finalize global row t (lr = t&127)
      const int lr = t & 127;
      float sum = ((pacc[par][0][lr] + pacc[par][1][lr]) +
                   (pacc[par][2][lr] + pacc[par][3][lr])) +
                  ((pacc[par][4][lr] + pacc[par][5][lr]) +
                   (pacc[par][6][lr] + pacc[par][7][lr]));
      float h = tanh_fast(sum + xq0);
      STOREA(&g_pub[b][par][t],                     // publish ASAP (peers spin on this)
             ((unsigned long long)(unsigned)(s + 1) << 32) |
             (unsigned long long)__builtin_bit_cast(unsigned, h));
      hl[par ^ 1][t] = h;                           // own slice for next step (same wave)
      xp[(size_t)s * 256] = h;                      // hs for phase C (fire-and-forget)
      xq0 = xq1;
      if (s + 2 < NT) xq1 = xp[(size_t)(s + 2) * 256];   // 2-step HBM prefetch
    }
    // no end-of-step barrier: partner waves race ahead to next probe (overlaps finalize)
  }
}

// ---------------- Phase C: out-projection (f16 dot2, f32 out, in-place; proven) ------------
__global__ __launch_bounds__(256) void k_outproj(
    const float* hlo, const float* hhi, const float* __restrict__ w,
    const float* __restrict__ bias, float* out)
{
  __shared__ half2_t xs[32][258];
  __shared__ half2_t ws[256][19];
  const int t = threadIdx.x;
  const int m0 = blockIdx.x * 32;
  const int nthr = t >> 2;
  const int mthr = t & 3;

  #pragma unroll
  for (int r = 0; r < 16; ++r) {
    int f = (t + 256 * r) * 4;
    int row = f >> 9, col = f & 511;
    const float* src = (col < 256) ? (hlo + (size_t)(m0 + row) * 256 + col)
                                   : (hhi + (size_t)(m0 + row) * 256 + (col - 256));
    float4_t v = *reinterpret_cast<const float4_t*>(src);
    xs[row][(col >> 1)]     = half2_t{(f16)v.x, (f16)v.y};
    xs[row][(col >> 1) + 1] = half2_t{(f16)v.z, (f16)v.w};
  }

  float acc[4][8];
  #pragma unroll
  for (int nn = 0; nn < 4; ++nn) {
    float bv = bias[nthr * 4 + nn];
    #pragma unroll
    for (int mm = 0; mm < 8; ++mm) acc[nn][mm] = bv;
  }

  for (int kc = 0; kc < 16; ++kc) {
    __syncthreads();
    #pragma unroll
    for (int r = 0; r < 8; ++r) {
      int f = (t + 256 * r) * 4;
      int row = f >> 5, col = f & 31;
      float4_t v = *reinterpret_cast<const float4_t*>(w + (size_t)row * NHID + kc * 32 + col);
      ws[row][(col >> 1)]     = half2_t{(f16)v.x, (f16)v.y};
      ws[row][(col >> 1) + 1] = half2_t{(f16)v.z, (f16)v.w};
    }
    __syncthreads();
    #pragma unroll
    for (int kp = 0; kp < 16; ++kp) {
      half2_t wv[4], xv[8];
      #pragma unroll
      for (int nn = 0; nn < 4; ++nn) wv[nn] = ws[nthr * 4 + nn][kp];
      #pragma unroll
      for (int mm = 0; mm < 8; ++mm) xv[mm] = xs[mthr * 8 + mm][kc * 16 + kp];
      #pragma unroll
      for (int nn = 0; nn < 4; ++nn)
        #pragma unroll
        for (int mm = 0; mm < 8; ++mm)
          acc[nn][mm] = fdot2f(wv[nn], xv[mm], acc[nn][mm]);
    }
  }

  #pragma unroll
  for (int mm = 0; mm < 8; ++mm) {
    int m = m0 + mthr * 8 + mm;
    float4_t o = {acc[0][mm], acc[1][mm], acc[2][mm], acc[3][mm]};
    *reinterpret_cast<float4_t*>(out + (size_t)m * NOUT + nthr * 4) = o;
  }
}

extern "C" void kernel_launch(void* const* d_in, const int* in_sizes, int n_in,
                              void* d_out, int out_size, void* d_ws, size_t ws_size,
                              hipStream_t stream) {
  (void)in_sizes; (void)n_in; (void)ws_size; (void)out_size;
  const float* x     = (const float*)d_in[0];
  const float* w_ih  = (const float*)d_in[1];
  const float* w_hh  = (const float*)d_in[2];
  const float* b_h   = (const float*)d_in[3];
  const float* w_out = (const float*)d_in[4];
  const float* b_out = (const float*)d_in[5];

  float* outb = (float*)d_out;   // xp cols 0..255  -> h rows 0..255  -> y   (134 MB)
  float* wsb  = (float*)d_ws;    // xp cols 256..511 -> h rows 256..511     (134 MB, proven)

  k_zero   <<<256, 256, 0, stream>>>();
  k_inproj <<<(NBATCH * NT) / 32, 256, 0, stream>>>(x, w_ih, b_h, outb, wsb);
  k_recur  <<<256, 512, 0, stream>>>(w_hh, outb, wsb);
  k_outproj<<<(NBATCH * NT) / 32, 256, 0, stream>>>(outb, wsb, w_out, b_out, outb);
}